// Round 15
// baseline (16.647 us; speedup 1.0000x reference)
//
#include <hip/hip_runtime.h>
#include <math.h>

// MaxYager2d: out[b,f,si,sj] = max(0, 1 - (min_{c,kh,kw} A[b,c,si+kh,sj+kw] + BW[c,kh,kw,f])^(2/3))
// A = (1-x)^1.5, BW = (1-w)^1.5. Max over J commutes with the monotone-
// decreasing Yager combine -> tropical min-plus 3x3 conv.
//
// r15 = r14 + f-per-wave 2 -> 4 (outputs/LDS-instr again):
//  - wave = 4 f x 2 rows x 64 cols = 512 outputs; A-reads/output halve
//    (48 b128 amortized 2x); B/output constant. Per-CU LDS 7.5k -> 5.2k cy.
//  - block 256 thr (4 waves x 4f = 16f, fh split keeps grid at 256);
//    small blocks co-reside 2-4/CU -> tail absorption + stage overlap.
//  - __launch_bounds__(256,4): VGPR cap 128, live set ~95 -> no spill.
// Same value set as r14 -> absmax 0.00390625 unchanged.

#define CIN  32
#define FOUT 32
#define KS   3
#define HW   66
#define SS   64
#define NB   4

typedef _Float16 half2_t __attribute__((ext_vector_type(2)));
typedef _Float16 half8_t __attribute__((ext_vector_type(8)));

static __device__ __forceinline__ _Float16 yg(float v) {
    float t = 1.0f - v;
    return (_Float16)(t * sqrtf(t));   // (1-v)^1.5
}

union bv8 {
    half8_t v8;
    half2_t v2[4];
};

__global__ __launch_bounds__(256, 4) void yager_one(
    const float* __restrict__ x, const float* __restrict__ w,
    float* __restrict__ out)
{
    __shared__ __align__(16) half8_t ldsA[4][4][68];   // 17.4 KB [q(8ch)][row][col]
    __shared__ __align__(16) half2_t ldsB[16][148];    // 9.5 KB  [fi][t*16+4q+c4] (pad 4)

    const int tid  = threadIdx.x;
    const int fh   = blockIdx.x & 1;          // f-half (16 f per block)
    const int pair = (blockIdx.x >> 1) & 31;  // output row pair
    const int b    = blockIdx.x >> 6;

    // --- stage B (block's 16 f): 4608 f16, 18/thread, coalesced w reads.
    // Write f16 at fi*296 + t*32 + c halfs: fi-stride 592B -> 8 banks (2-way).
#pragma unroll
    for (int k = 0; k < 18; ++k) {
        int i  = tid + k * 256;
        int fi = i & 15;
        int j  = i >> 4;                      // c*9 + t, 0..287
        int c  = j / 9;
        int t  = j - 9 * c;
        float v = w[j * FOUT + fh * 16 + fi];
        ((_Float16*)ldsB)[fi * 296 + t * 32 + c] = yg(v);
    }

    // --- stage A: input rows 2p..2p+3, 8-ch half8 slots q=0..3 (1056 half8).
    for (int i = tid; i < 4 * 4 * HW; i += 256) {
        int q   = i / (4 * HW);
        int r   = i - q * (4 * HW);
        int row = r / HW;
        int col = r - row * HW;
        const float* xp = x + (((size_t)b * CIN + 8 * q) * HW + 2 * pair + row) * HW + col;
        half8_t v;
#pragma unroll
        for (int k = 0; k < 8; ++k)
            v[k] = yg(xp[(size_t)k * HW * HW]);
        ldsA[q][row][col] = v;
    }
    __syncthreads();

    const int lane = tid & 63;                                  // output col
    const int wv   = __builtin_amdgcn_readfirstlane(tid >> 6);  // 0..3
    const int f0   = wv * 4;                                    // local f quad

    // acc[r][ff][parity]: 16 independent half2 min-chains
    half2_t acc[2][4][2];
#pragma unroll
    for (int r = 0; r < 2; ++r)
#pragma unroll
        for (int ff = 0; ff < 4; ++ff)
#pragma unroll
            for (int p = 0; p < 2; ++p) {
                half2_t z; z.x = (_Float16)4.0f; z.y = (_Float16)4.0f;
                acc[r][ff][p] = z;
            }

#pragma unroll
    for (int q = 0; q < 4; ++q) {
        // A tile: 4 LDS rows x 3 kw (serves both output rows), 12 b128
        half8_t a[4][KS];
#pragma unroll
        for (int rr = 0; rr < 4; ++rr)
#pragma unroll
            for (int kw = 0; kw < KS; ++kw)
                a[rr][kw] = ldsA[q][rr][lane + kw];
#pragma unroll
        for (int t = 0; t < 9; ++t) {
            const int kr = t / 3, kw = t % 3;
            bv8 B[4];                          // wave-uniform broadcast b128 x4
#pragma unroll
            for (int ff = 0; ff < 4; ++ff)
                B[ff].v8 = *(const half8_t*)&ldsB[f0 + ff][t * 16 + 4 * q];
#pragma unroll
            for (int r = 0; r < 2; ++r) {
                bv8 av; av.v8 = a[kr + r][kw];
#pragma unroll
                for (int ff = 0; ff < 4; ++ff)
#pragma unroll
                    for (int c4 = 0; c4 < 4; ++c4) {
                        half2_t s = av.v2[c4] + B[ff].v2[c4];
                        acc[r][ff][c4 & 1] =
                            __builtin_elementwise_min(acc[r][ff][c4 & 1], s);
                    }
            }
        }
    }

#pragma unroll
    for (int r = 0; r < 2; ++r)
#pragma unroll
        for (int ff = 0; ff < 4; ++ff) {
            half2_t M = __builtin_elementwise_min(acc[r][ff][0], acc[r][ff][1]);
            float m = fminf((float)M.x, (float)M.y);
            float rv = 1.0f - exp2f(0.6666666667f * log2f(m));
            out[(((size_t)b * FOUT + fh * 16 + f0 + ff) * SS + 2 * pair + r) * SS + lane]
                = fmaxf(rv, 0.0f);
        }
}

extern "C" void kernel_launch(void* const* d_in, const int* in_sizes, int n_in,
                              void* d_out, int out_size, void* d_ws, size_t ws_size,
                              hipStream_t stream)
{
    const float* x = (const float*)d_in[0];   // [4,32,66,66] f32
    const float* w = (const float*)d_in[1];   // [288,32] f32
    float* out = (float*)d_out;               // [4,32,64,64] f32
    (void)d_ws; (void)ws_size;

    yager_one<<<NB * 32 * 2, 256, 0, stream>>>(x, w, out);
}

// Round 16
// 16.207 us; speedup vs baseline: 1.0272x; 1.0272x over previous
//
#include <hip/hip_runtime.h>
#include <math.h>

// MaxYager2d: out[b,f,si,sj] = max(0, 1 - (min_{c,kh,kw} A[b,c,si+kh,sj+kw] + BW[c,kh,kw,f])^(2/3))
// A = (1-x)^1.5, BW = (1-w)^1.5. Max over J commutes with the monotone-
// decreasing Yager combine -> tropical min-plus 3x3 conv.
//
// r16 = r14's per-wave economics (2f x 2rows x 64cols per wave; half8 A,
// b128 broadcast B) with 4-wave blocks instead of 8:
//  - grid 512 = b(4) x pair(32) x fq(4), 256 thr: 2 blocks/CU -> one
//    block's staging overlaps the other's compute; 4-wave barriers;
//    finer dispatch tail. Total waves 2048 = 2/SIMD (r14's sweet spot —
//    r15 showed 1/SIMD loses more than LDS-instr savings gain).
//  - ldsB fi-stride 296 halfs = 148 dw = 20 mod 32 -> 8 fi lanes on 8
//    distinct banks (conflict-free scatter).
// Inner arithmetic identical to r14 -> absmax 0.00390625 unchanged.

#define CIN  32
#define FOUT 32
#define KS   3
#define HW   66
#define SS   64
#define NB   4

typedef _Float16 half2_t __attribute__((ext_vector_type(2)));
typedef _Float16 half8_t __attribute__((ext_vector_type(8)));

static __device__ __forceinline__ _Float16 yg(float v) {
    float t = 1.0f - v;
    return (_Float16)(t * sqrtf(t));   // (1-v)^1.5
}

union bv8 {
    half8_t v8;
    half2_t v2[4];
};

__global__ __launch_bounds__(256) void yager_one(
    const float* __restrict__ x, const float* __restrict__ w,
    float* __restrict__ out)
{
    __shared__ __align__(16) half8_t ldsA[4][4][68];   // 17.4 KB [q(8ch)][row][col]
    __shared__ __align__(16) half2_t ldsB[8][148];     // 4.7 KB  [fi][t*16+4q+c4] (pad 4)

    const int tid  = threadIdx.x;
    const int fq   = blockIdx.x & 3;          // f-quarter (8 f per block)
    const int pair = (blockIdx.x >> 2) & 31;  // output row pair
    const int b    = blockIdx.x >> 7;

    // --- stage B (block's 8 f): 2304 f16, 9/thread, coalesced-ish w reads
    // (8 consecutive f32 per j). fi-stride 148 dw -> 8 lanes on 8 banks.
#pragma unroll
    for (int k = 0; k < 9; ++k) {
        int i  = tid + k * 256;
        int fi = i & 7;
        int j  = i >> 3;                      // c*9 + t, 0..287
        int c  = j / 9;
        int t  = j - 9 * c;
        float v = w[j * FOUT + fq * 8 + fi];
        ((_Float16*)ldsB)[fi * 296 + t * 32 + c] = yg(v);
    }

    // --- stage A: input rows 2p..2p+3, 8-ch half8 slots q=0..3 (1056 half8).
    for (int i = tid; i < 4 * 4 * HW; i += 256) {
        int q   = i / (4 * HW);
        int r   = i - q * (4 * HW);
        int row = r / HW;
        int col = r - row * HW;
        const float* xp = x + (((size_t)b * CIN + 8 * q) * HW + 2 * pair + row) * HW + col;
        half8_t v;
#pragma unroll
        for (int k = 0; k < 8; ++k)
            v[k] = yg(xp[(size_t)k * HW * HW]);
        ldsA[q][row][col] = v;
    }
    __syncthreads();

    const int lane = tid & 63;                                  // output col
    const int wv   = __builtin_amdgcn_readfirstlane(tid >> 6);  // 0..3
    const int f0   = wv * 2;                                    // local f pair (of 8)

    // acc[r][f][parity]: 8 independent half2 min-chains
    half2_t acc[2][2][2];
#pragma unroll
    for (int r = 0; r < 2; ++r)
#pragma unroll
        for (int f = 0; f < 2; ++f)
#pragma unroll
            for (int p = 0; p < 2; ++p) {
                half2_t z; z.x = (_Float16)4.0f; z.y = (_Float16)4.0f;
                acc[r][f][p] = z;
            }

#pragma unroll
    for (int q = 0; q < 4; ++q) {
        // A tile: 4 LDS rows x 3 kw (serves both output rows), 12 b128
        half8_t a[4][KS];
#pragma unroll
        for (int rr = 0; rr < 4; ++rr)
#pragma unroll
            for (int kw = 0; kw < KS; ++kw)
                a[rr][kw] = ldsA[q][rr][lane + kw];
#pragma unroll
        for (int t = 0; t < 9; ++t) {
            const int kr = t / 3, kw = t % 3;
            bv8 B0, B1;                       // wave-uniform broadcast b128
            B0.v8 = *(const half8_t*)&ldsB[f0][t * 16 + 4 * q];
            B1.v8 = *(const half8_t*)&ldsB[f0 + 1][t * 16 + 4 * q];
#pragma unroll
            for (int r = 0; r < 2; ++r) {
                bv8 av; av.v8 = a[kr + r][kw];
#pragma unroll
                for (int c4 = 0; c4 < 4; ++c4) {
                    half2_t s0 = av.v2[c4] + B0.v2[c4];
                    half2_t s1 = av.v2[c4] + B1.v2[c4];
                    acc[r][0][c4 & 1] = __builtin_elementwise_min(acc[r][0][c4 & 1], s0);
                    acc[r][1][c4 & 1] = __builtin_elementwise_min(acc[r][1][c4 & 1], s1);
                }
            }
        }
    }

#pragma unroll
    for (int r = 0; r < 2; ++r)
#pragma unroll
        for (int f = 0; f < 2; ++f) {
            half2_t M = __builtin_elementwise_min(acc[r][f][0], acc[r][f][1]);
            float m = fminf((float)M.x, (float)M.y);
            float rv = 1.0f - exp2f(0.6666666667f * log2f(m));
            out[(((size_t)b * FOUT + fq * 8 + f0 + f) * SS + 2 * pair + r) * SS + lane]
                = fmaxf(rv, 0.0f);
        }
}

extern "C" void kernel_launch(void* const* d_in, const int* in_sizes, int n_in,
                              void* d_out, int out_size, void* d_ws, size_t ws_size,
                              hipStream_t stream)
{
    const float* x = (const float*)d_in[0];   // [4,32,66,66] f32
    const float* w = (const float*)d_in[1];   // [288,32] f32
    float* out = (float*)d_out;               // [4,32,64,64] f32
    (void)d_ws; (void)ws_size;

    yager_one<<<NB * 32 * 4, 256, 0, stream>>>(x, w, out);
}

// Round 17
// 14.452 us; speedup vs baseline: 1.1519x; 1.1214x over previous
//
#include <hip/hip_runtime.h>
#include <math.h>

// MaxYager2d: out[b,f,si,sj] = max(0, 1 - (min_{c,kh,kw} A[b,c,si+kh,sj+kw] + BW[c,kh,kw,f])^(2/3))
// A = (1-x)^1.5, BW = (1-w)^1.5. Max over J commutes with the monotone-
// decreasing Yager combine -> tropical min-plus 3x3 conv.
//
// r17 = r14 (best, 14.36 us) with ONE change: __launch_bounds__(512, 6).
// r14's (512,2) let the allocator use >128 VGPRs -> 2 blocks/CU (4 waves/
// SIMD). Live set is ~55 regs, so capping at 85 (6 waves/EU) costs nothing
// and fits 3 blocks/CU = 6 waves/SIMD -> +50% latency hiding on the
// ds_read->pk_min chains and staging loads. Kernel is latency-bound
// (~9.5 us vs 3.1 us LDS-issue floor), so occupancy is the remaining dial.
// Arithmetic byte-identical to r14 -> absmax 0.00390625 unchanged.
//
//  - wave = 2f x 2rows x 64cols; A packed half8 (8ch/slot, b128 reads);
//    B wave-uniform broadcast b128; 48 A + 72 B LDS reads per 256 outputs.
//  - grid 256 = b(4) x pair(32) x fh(2), 512 thr = 8 waves.
//  - ldsB fi-stride 296 halfs (592 B): scatter-writes 2-way (free);
//    b128 reads 16B-aligned.

#define CIN  32
#define FOUT 32
#define KS   3
#define HW   66
#define SS   64
#define NB   4

typedef _Float16 half2_t __attribute__((ext_vector_type(2)));
typedef _Float16 half8_t __attribute__((ext_vector_type(8)));

static __device__ __forceinline__ _Float16 yg(float v) {
    float t = 1.0f - v;
    return (_Float16)(t * sqrtf(t));   // (1-v)^1.5
}

union bv8 {
    half8_t v8;
    half2_t v2[4];
};

__global__ __launch_bounds__(512, 6) void yager_one(
    const float* __restrict__ x, const float* __restrict__ w,
    float* __restrict__ out)
{
    __shared__ __align__(16) half8_t ldsA[4][4][68];   // 17.4 KB [q(8ch)][row][col]
    __shared__ __align__(16) half2_t ldsB[16][148];    // 9.5 KB  [fi][t*16+4q+c4] (pad 4)

    const int tid  = threadIdx.x;
    const int fh   = blockIdx.x & 1;          // f-half
    const int pair = (blockIdx.x >> 1) & 31;  // output row pair
    const int b    = blockIdx.x >> 6;

    // --- stage B (this block's 16 f): 4608 elems, 9/thread, coalesced reads.
    // Write f16 at fi*296 + t*32 + c halfs: fi-stride 592 B -> 2-way (free).
#pragma unroll
    for (int k = 0; k < 9; ++k) {
        int i  = tid + k * 512;
        int fi = i & 15;
        int j  = i >> 4;                      // c*9 + t, 0..287
        int c  = j / 9;
        int t  = j - 9 * c;
        float v = w[j * FOUT + fh * 16 + fi];
        ((_Float16*)ldsB)[fi * 296 + t * 32 + c] = yg(v);
    }

    // --- stage A: input rows 2p..2p+3, channels as half8 slots q=0..3.
    for (int i = tid; i < 4 * 4 * HW; i += 512) {
        int q   = i / (4 * HW);
        int r   = i - q * (4 * HW);
        int row = r / HW;
        int col = r - row * HW;
        const float* xp = x + (((size_t)b * CIN + 8 * q) * HW + 2 * pair + row) * HW + col;
        half8_t v;
#pragma unroll
        for (int k = 0; k < 8; ++k)
            v[k] = yg(xp[(size_t)k * HW * HW]);
        ldsA[q][row][col] = v;
    }
    __syncthreads();

    const int lane = tid & 63;                                  // output col
    const int wv   = __builtin_amdgcn_readfirstlane(tid >> 6);  // 0..7
    const int f0   = wv * 2;                                    // local f pair

    // acc[r][f][parity] as 8 independent half2 min-chains
    half2_t acc[2][2][2];
#pragma unroll
    for (int r = 0; r < 2; ++r)
#pragma unroll
        for (int f = 0; f < 2; ++f)
#pragma unroll
            for (int p = 0; p < 2; ++p) {
                half2_t z; z.x = (_Float16)4.0f; z.y = (_Float16)4.0f;
                acc[r][f][p] = z;
            }

#pragma unroll
    for (int q = 0; q < 4; ++q) {
        // A tile: 4 LDS rows x 3 kw, serves both output rows
        half8_t a[4][KS];
#pragma unroll
        for (int rr = 0; rr < 4; ++rr)
#pragma unroll
            for (int kw = 0; kw < KS; ++kw)
                a[rr][kw] = ldsA[q][rr][lane + kw];
#pragma unroll
        for (int t = 0; t < 9; ++t) {
            const int kr = t / 3, kw = t % 3;
            bv8 B0, B1;                       // wave-uniform broadcast b128
            B0.v8 = *(const half8_t*)&ldsB[f0][t * 16 + 4 * q];
            B1.v8 = *(const half8_t*)&ldsB[f0 + 1][t * 16 + 4 * q];
#pragma unroll
            for (int r = 0; r < 2; ++r) {
                bv8 av; av.v8 = a[kr + r][kw];
#pragma unroll
                for (int c4 = 0; c4 < 4; ++c4) {
                    half2_t s0 = av.v2[c4] + B0.v2[c4];
                    half2_t s1 = av.v2[c4] + B1.v2[c4];
                    acc[r][0][c4 & 1] = __builtin_elementwise_min(acc[r][0][c4 & 1], s0);
                    acc[r][1][c4 & 1] = __builtin_elementwise_min(acc[r][1][c4 & 1], s1);
                }
            }
        }
    }

#pragma unroll
    for (int r = 0; r < 2; ++r)
#pragma unroll
        for (int f = 0; f < 2; ++f) {
            half2_t M = __builtin_elementwise_min(acc[r][f][0], acc[r][f][1]);
            float m = fminf((float)M.x, (float)M.y);
            float rv = 1.0f - exp2f(0.6666666667f * log2f(m));
            out[(((size_t)b * FOUT + fh * 16 + f0 + f) * SS + 2 * pair + r) * SS + lane]
                = fmaxf(rv, 0.0f);
        }
}

extern "C" void kernel_launch(void* const* d_in, const int* in_sizes, int n_in,
                              void* d_out, int out_size, void* d_ws, size_t ws_size,
                              hipStream_t stream)
{
    const float* x = (const float*)d_in[0];   // [4,32,66,66] f32
    const float* w = (const float*)d_in[1];   // [288,32] f32
    float* out = (float*)d_out;               // [4,32,64,64] f32
    (void)d_ws; (void)ws_size;

    yager_one<<<NB * 32 * 2, 512, 0, stream>>>(x, w, out);
}